// Round 6
// baseline (144.479 us; speedup 1.0000x reference)
//
#include <hip/hip_runtime.h>
#include <math.h>

#define N_TRIAL 1000000
#define N_REF 8
#define N_DIM 16
#define N_GROUP 4
#define BETA 1.0f
#define GAMMA 0.001f
// N_SELECT = {1,2,3,1} packed as nibbles
#define N_SELECT_PACKED 0x1321

#define WPB 4          // waves per block
#define D2_STRIDE 72   // 64+8: write banks (16s+16j+q)%32 and read banks (8r+lane)%32 both 2-way = free

typedef float v4f __attribute__((ext_vector_type(4)));

// Round-6 structure: barrier-free per-wave two-phase kernel with a 2-deep
// software pipeline over the 4 quad-gather passes. Rounds 3-5 showed every
// pipe (VALU 35%, TA ~31%, L2 ~29%) stuck at ~1/3 -- latency-serialized.
// Here pass j+1's 9 gathers are in flight while pass j computes, and pass
// j+2's are issued before pass j+1 is consumed (18 outstanding loads/wave).
__global__ __launch_bounds__(256, 3) void likelihood_kernel(
    const int* __restrict__ stim,     // N_TRIAL x 9
    const int* __restrict__ config,   // N_TRIAL
    const int* __restrict__ group,    // N_TRIAL
    const int* __restrict__ present,  // N_TRIAL x 9
    const float* __restrict__ embed,  // N_STIM x 16
    const float* __restrict__ attw,   // N_GROUP x 16
    float* __restrict__ out)          // N_TRIAL
{
    __shared__ int4  s_stim4[WPB][144];            // 64 trials x 9 ints, dense
    __shared__ int4  s_pres4[WPB][144];            // same for present
    __shared__ float s_d2[WPB][N_REF][D2_STRIDE];  // [ref][trial] transpose

    const int tid  = threadIdx.x;
    const int wv   = tid >> 6;
    const int lane = tid & 63;
    const int q    = lane >> 2;   // quad id 0..15
    const int s    = lane & 3;    // float4 segment 0..3

    int wtb = blockIdx.x * 256 + wv * 64;          // this wave's 64 trials
    const bool valid = (wtb + lane) < N_TRIAL;
    if (wtb > N_TRIAL - 64) wtb = N_TRIAL - 64;    // clamp (N_TRIAL % 64 == 0)

    // ---- dense coalesced staging: each stream cache line touched ONCE ----
    {
        const int4* g4 = (const int4*)(stim + wtb * 9);      // 144 int4/wave
        s_stim4[wv][lane]      = g4[lane];
        s_stim4[wv][64 + lane] = g4[64 + lane];
        if (lane < 16) s_stim4[wv][128 + lane] = g4[128 + lane];
        const int4* p4 = (const int4*)(present + wtb * 9);
        s_pres4[wv][lane]      = p4[lane];
        s_pres4[wv][64 + lane] = p4[64 + lane];
        if (lane < 16) s_pres4[wv][128 + lane] = p4[128 + lane];
    }

    const int t2 = wtb + lane;                     // phase-2 trial
    int c    = config[t2];
    int gall = group[t2];                          // redistributed via __shfl

    // attw is 256 B: preload ALL 4 groups' segments, select by cndmask later
    // (removes a vmem load from the compute body)
    v4f wt0 = *(const v4f*)(attw + 0 * N_DIM + s * 4);
    v4f wt1 = *(const v4f*)(attw + 1 * N_DIM + s * 4);
    v4f wt2 = *(const v4f*)(attw + 2 * N_DIM + s * 4);
    v4f wt3 = *(const v4f*)(attw + 3 * N_DIM + s * 4);

    const float* embed_s  = embed + s * 4;         // this lane's row segment
    const int*   stim_lds = (const int*)&s_stim4[wv][0];

    v4f z0[9], z1[9];
    int idx[9];

    // ---- pipeline prologue: issue gathers for passes 0 and 1 ----
#pragma unroll
    for (int i = 0; i < 9; ++i) idx[i] = stim_lds[(16 * 0 + q) * 9 + i];
#pragma unroll
    for (int i = 0; i < 9; ++i) z0[i] = *(const v4f*)(embed_s + idx[i] * N_DIM);
#pragma unroll
    for (int i = 0; i < 9; ++i) idx[i] = stim_lds[(16 * 1 + q) * 9 + i];
#pragma unroll
    for (int i = 0; i < 9; ++i) z1[i] = *(const v4f*)(embed_s + idx[i] * N_DIM);

    auto compute = [&](int j, v4f* z) {
        int g = __shfl(gall, 16 * j + q);          // quad-uniform group id
        v4f w = (g == 0) ? wt0 : (g == 1) ? wt1 : (g == 2) ? wt2 : wt3;
        v4f zq = z[0];
        float d2v[N_REF];
#pragma unroll
        for (int r = 0; r < N_REF; ++r) {
            v4f dd = zq - z[1 + r];
            v4f wd = w * dd;
            float d2 = (wd.x * dd.x + wd.y * dd.y) + (wd.z * dd.z + wd.w * dd.w);
            d2 += __shfl_xor(d2, 1);               // quad butterfly: 16-dim sum
            d2 += __shfl_xor(d2, 2);
            d2v[r] = d2;
        }
        // lane s persists rows 2s, 2s+1 (uses the quad replication)
        float da = (s == 0) ? d2v[0] : (s == 1) ? d2v[2] : (s == 2) ? d2v[4] : d2v[6];
        float db = (s == 0) ? d2v[1] : (s == 1) ? d2v[3] : (s == 2) ? d2v[5] : d2v[7];
        s_d2[wv][2 * s    ][16 * j + q] = da;
        s_d2[wv][2 * s + 1][16 * j + q] = db;
    };

    // ---- steady state: compute pass j, issue pass j+2 ----
    compute(0, z0);
#pragma unroll
    for (int i = 0; i < 9; ++i) idx[i] = stim_lds[(16 * 2 + q) * 9 + i];
#pragma unroll
    for (int i = 0; i < 9; ++i) z0[i] = *(const v4f*)(embed_s + idx[i] * N_DIM);
    compute(1, z1);
#pragma unroll
    for (int i = 0; i < 9; ++i) idx[i] = stim_lds[(16 * 3 + q) * 9 + i];
#pragma unroll
    for (int i = 0; i < 9; ++i) z1[i] = *(const v4f*)(embed_s + idx[i] * N_DIM);
    compute(2, z0);
    compute(3, z1);
    // intra-wave ds_write -> ds_read ordering via compiler lgkmcnt; no barrier

    // ---------------- Phase 2: thread-per-trial tail -----------------------
    const int* pres_lds = (const int*)&s_pres4[wv][0] + lane * 9;  // stride 9: 2-way banks = free

    float sim[N_REF];
#pragma unroll
    for (int r = 0; r < N_REF; ++r) {
        float d2 = s_d2[wv][r][lane];
        sim[r] = (__expf(-BETA * sqrtf(d2)) + GAMMA) * (float)pres_lds[1 + r];
    }

    int ns = (N_SELECT_PACKED >> ((c & 3) * 4)) & 0xF;   // ns in {1,2,3}

    // only suffix[0..2] can be selected (max N_SELECT == 3)
    float suf2 = sim[7];
#pragma unroll
    for (int r = 6; r >= 2; --r) suf2 += sim[r];
    float suf1 = suf2 + sim[1];
    float suf0 = suf1 + sim[0];

    float num = sim[0] * ((ns >= 2) ? sim[1] : 1.0f) * ((ns >= 3) ? sim[2] : 1.0f);
    float den = suf0   * ((ns >= 2) ? suf1   : 1.0f) * ((ns >= 3) ? suf2   : 1.0f);

    if (valid)
        out[wtb + lane] = __fdividef(num, den);   // fully coalesced store
}

extern "C" void kernel_launch(void* const* d_in, const int* in_sizes, int n_in,
                              void* d_out, int out_size, void* d_ws, size_t ws_size,
                              hipStream_t stream) {
    const int*   stim    = (const int*)d_in[0];
    const int*   config  = (const int*)d_in[1];
    const int*   group   = (const int*)d_in[2];
    const int*   present = (const int*)d_in[3];
    const float* embed   = (const float*)d_in[4];
    const float* attw    = (const float*)d_in[5];
    float*       out     = (float*)d_out;

    int blocks = (N_TRIAL + 255) / 256;   // 3907; tail handled by clamp+valid
    likelihood_kernel<<<blocks, 256, 0, stream>>>(stim, config, group, present,
                                                  embed, attw, out);
}

// Round 7
// 144.161 us; speedup vs baseline: 1.0022x; 1.0022x over previous
//
#include <hip/hip_runtime.h>
#include <math.h>

#define N_TRIAL 1000000
#define N_STIM 10000
#define N_REF 8
#define N_DIM 16
#define N_GROUP 4
#define BETA 1.0f
#define GAMMA 0.001f
// N_SELECT = {1,2,3,1} packed as nibbles
#define N_SELECT_PACKED 0x1321

#define WPB 4          // waves per block
#define D2_STRIDE 72   // 64+8: write banks (16s+q)%32 and read banks (8r+lane)%32 both 2-way = free

typedef float v4f __attribute__((ext_vector_type(4)));

// ---------------------------------------------------------------------------
// Kernel 1: fp32 embed -> bf16 (RNE) table in workspace. 160k elems, ~3 us.
// Rebuilt every launch (ws is re-poisoned; same work every call).
// ---------------------------------------------------------------------------
__global__ __launch_bounds__(256) void convert_kernel(
    const float* __restrict__ embed, unsigned int* __restrict__ ebf)
{
    int i = blockIdx.x * 256 + threadIdx.x;      // one packed uint (2 elems)/thread
    if (i >= N_STIM * N_DIM / 2) return;
    unsigned int b0 = __builtin_bit_cast(unsigned int, embed[2 * i]);
    unsigned int b1 = __builtin_bit_cast(unsigned int, embed[2 * i + 1]);
    b0 = (b0 + 0x7fffu + ((b0 >> 16) & 1u)) >> 16;   // RNE to bf16
    b1 = (b1 + 0x7fffu + ((b1 >> 16) & 1u)) >> 16;
    ebf[i] = b0 | (b1 << 16);
}

__device__ __forceinline__ v4f bf16x4_to_f32(uint2 u) {
    v4f z;
    z.x = __builtin_bit_cast(float, u.x << 16);
    z.y = __builtin_bit_cast(float, u.x & 0xffff0000u);
    z.z = __builtin_bit_cast(float, u.y << 16);
    z.w = __builtin_bit_cast(float, u.y & 0xffff0000u);
    return z;
}

// ---------------------------------------------------------------------------
// Kernel 2: round-5 structure (best: 58 us) with bf16 gathers (8 B/lane).
//   staging : wave's stim+present rows copied dense+coalesced into LDS
//   phase 1 : quad-per-trial gathers (9 rows/trial) + weighted distance
//   phase 2 : thread-per-trial tail (no 4x replication of sqrt/exp/suffix)
// Barrier-free: all LDS dependencies are intra-wave.
// ---------------------------------------------------------------------------
__global__ __launch_bounds__(256) void likelihood_kernel(
    const int* __restrict__ stim,     // N_TRIAL x 9
    const int* __restrict__ config,   // N_TRIAL
    const int* __restrict__ group,    // N_TRIAL
    const int* __restrict__ present,  // N_TRIAL x 9
    const uint2* __restrict__ ebf,    // N_STIM x 16 bf16 (4 x uint2 per row)
    const float* __restrict__ attw,   // N_GROUP x 16
    float* __restrict__ out)          // N_TRIAL
{
    __shared__ int4  s_stim4[WPB][144];            // 64 trials x 9 ints, dense
    __shared__ int4  s_pres4[WPB][144];            // same for present
    __shared__ float s_d2[WPB][N_REF][D2_STRIDE];  // [ref][trial] transpose

    const int tid  = threadIdx.x;
    const int wv   = tid >> 6;
    const int lane = tid & 63;
    const int q    = lane >> 2;   // quad id 0..15
    const int s    = lane & 3;    // bf16x4 segment 0..3

    int wtb = blockIdx.x * 256 + wv * 64;          // this wave's 64 trials
    const bool valid = (wtb + lane) < N_TRIAL;
    if (wtb > N_TRIAL - 64) wtb = N_TRIAL - 64;    // clamp (N_TRIAL % 64 == 0)

    // ---- dense coalesced staging: each stream cache line touched ONCE ----
    {
        const int4* g4 = (const int4*)(stim + wtb * 9);      // 144 int4/wave
        s_stim4[wv][lane]      = g4[lane];
        s_stim4[wv][64 + lane] = g4[64 + lane];
        if (lane < 16) s_stim4[wv][128 + lane] = g4[128 + lane];
        const int4* p4 = (const int4*)(present + wtb * 9);
        s_pres4[wv][lane]      = p4[lane];
        s_pres4[wv][64 + lane] = p4[64 + lane];
        if (lane < 16) s_pres4[wv][128 + lane] = p4[128 + lane];
    }

    const int t2 = wtb + lane;                     // phase-2 trial
    int c    = config[t2];
    int gall = group[t2];                          // redistributed via __shfl

    const uint2* ebf_s   = ebf + s;                // this lane's row segment
    const int*   stim_lds = (const int*)&s_stim4[wv][0];

    // ---------------- Phase 1: quad layout, 4 passes x 16 trials ----------
    for (int j = 0; j < 4; ++j) {
        const int* sp = stim_lds + (16 * j + q) * 9;
        int idx[9];
#pragma unroll
        for (int i = 0; i < 9; ++i) idx[i] = sp[i];   // 2-way banks = free

        int g  = __shfl(gall, 16 * j + q);            // quad-uniform group id
        v4f w  = *(const v4f*)(attw + g * N_DIM + s * 4);   // 256 B, L1-hot
        v4f zq = bf16x4_to_f32(ebf_s[idx[0] * 4]);

        float d2v[N_REF];
#pragma unroll
        for (int r = 0; r < N_REF; ++r) {
            v4f zr = bf16x4_to_f32(ebf_s[idx[1 + r] * 4]);
            v4f dd = zq - zr;
            v4f wd = w * dd;
            float d2 = (wd.x * dd.x + wd.y * dd.y) + (wd.z * dd.z + wd.w * dd.w);
            d2 += __shfl_xor(d2, 1);   // quad butterfly: full 16-dim sum
            d2 += __shfl_xor(d2, 2);
            d2v[r] = d2;
        }
        // lane s persists rows 2s, 2s+1 (uses the quad replication)
        float da = (s == 0) ? d2v[0] : (s == 1) ? d2v[2] : (s == 2) ? d2v[4] : d2v[6];
        float db = (s == 0) ? d2v[1] : (s == 1) ? d2v[3] : (s == 2) ? d2v[5] : d2v[7];
        s_d2[wv][2 * s    ][16 * j + q] = da;
        s_d2[wv][2 * s + 1][16 * j + q] = db;
    }
    // intra-wave ds_write -> ds_read ordering via compiler lgkmcnt; no barrier

    // ---------------- Phase 2: thread-per-trial tail -----------------------
    const int* pres_lds = (const int*)&s_pres4[wv][0] + lane * 9;  // stride 9: 2-way = free

    float sim[N_REF];
#pragma unroll
    for (int r = 0; r < N_REF; ++r) {
        float d2 = s_d2[wv][r][lane];
        sim[r] = (__expf(-BETA * sqrtf(d2)) + GAMMA) * (float)pres_lds[1 + r];
    }

    int ns = (N_SELECT_PACKED >> ((c & 3) * 4)) & 0xF;   // ns in {1,2,3}

    // only suffix[0..2] can be selected (max N_SELECT == 3)
    float suf2 = sim[7];
#pragma unroll
    for (int r = 6; r >= 2; --r) suf2 += sim[r];
    float suf1 = suf2 + sim[1];
    float suf0 = suf1 + sim[0];

    float num = sim[0] * ((ns >= 2) ? sim[1] : 1.0f) * ((ns >= 3) ? sim[2] : 1.0f);
    float den = suf0   * ((ns >= 2) ? suf1   : 1.0f) * ((ns >= 3) ? suf2   : 1.0f);

    if (valid)
        out[wtb + lane] = __fdividef(num, den);   // fully coalesced store
}

extern "C" void kernel_launch(void* const* d_in, const int* in_sizes, int n_in,
                              void* d_out, int out_size, void* d_ws, size_t ws_size,
                              hipStream_t stream) {
    const int*   stim    = (const int*)d_in[0];
    const int*   config  = (const int*)d_in[1];
    const int*   group   = (const int*)d_in[2];
    const int*   present = (const int*)d_in[3];
    const float* embed   = (const float*)d_in[4];
    const float* attw    = (const float*)d_in[5];
    float*       out     = (float*)d_out;

    unsigned int* ebf = (unsigned int*)d_ws;   // N_STIM*N_DIM*2 = 320,000 B

    int cblocks = (N_STIM * N_DIM / 2 + 255) / 256;
    convert_kernel<<<cblocks, 256, 0, stream>>>(embed, ebf);

    int blocks = (N_TRIAL + 255) / 256;   // 3907; tail handled by clamp+valid
    likelihood_kernel<<<blocks, 256, 0, stream>>>(stim, config, group, present,
                                                  (const uint2*)ebf, attw, out);
}